// Round 12
// baseline (236.655 us; speedup 1.0000x reference)
//
#include <hip/hip_runtime.h>
#include <math.h>

#define IMG   512
#define NFILT 32
#define PI_F  3.14159265358979323846f
#define GS    104      // LDS row stride in halves (208 B): b128 across lanes = 2-way banks (free)

typedef _Float16 v8h __attribute__((ext_vector_type(8)));
typedef float    v4f __attribute__((ext_vector_type(4)));

__device__ __forceinline__ unsigned pkrtz(float a, float b) {
    typedef __fp16 f16x2 __attribute__((ext_vector_type(2)));
    union { f16x2 h; unsigned u; } x;
    x.h = __builtin_amdgcn_cvt_pkrtz(a, b);
    return x.u;
}

template <int CTRL>
__device__ __forceinline__ float dpp_add(float v) {
    int t = __builtin_amdgcn_update_dpp(0, __float_as_int(v), CTRL, 0xf, 0xf, true);
    return v + __int_as_float(t);
}

#if __has_builtin(__builtin_amdgcn_sqrtf)
__device__ __forceinline__ float fsqrt(float x) { return __builtin_amdgcn_sqrtf(x); }
#else
__device__ __forceinline__ float fsqrt(float x) { return sqrtf(x); }
#endif

__device__ __forceinline__ v8h ldfrag(const uint4* p) {
    union { uint4 u; v8h h; } x; x.u = *p; return x.h;
}

__device__ __forceinline__ v8h neg8h(v8h a) {           // flip f16 sign bits
    union { v8h h; uint4 u; } x; x.h = a;
    x.u.x ^= 0x80008000u; x.u.y ^= 0x80008000u;
    x.u.z ^= 0x80008000u; x.u.w ^= 0x80008000u;
    return x.h;
}

// ---------------------------------------------------------------------------
// tabs layout (dwords): [filter:32][table:5][copy:8][block:20][dw:4]
//   tables: 0 g_re, 1 g_im, 2 f_re, 3 f_im, 4 -f_im (tbl4 kept for layout)
//   copy c, block i holds halves tap(8*i-64+c .. +7); tap(t)=0 unless 0<=t<32.
// One block per filter: compute 160 base taps into LDS once, expand by gather.
// ---------------------------------------------------------------------------
__global__ void make_tables(unsigned* __restrict__ tabs) {
    __shared__ _Float16 P[5][168];      // P[tbl][p] = tap(p-64), zero-padded
    const int fo = blockIdx.x;
    const int tid = threadIdx.x;
    for (int e = tid; e < 5 * 168; e += 256) ((_Float16*)P)[e] = (_Float16)0.0f;
    __syncthreads();
    if (tid < 160) {
        int tbl = tid >> 5, t = tid & 31;
        int s = (fo >> 3) + 1, o = fo & 7;
        float theta = (float)o * (PI_F / 7.0f);      // linspace(0, pi, 8)
        float sf = (float)s * 2.0f;                  // scale * SIGMA
        float kf = 2.0f * PI_F / ((float)s * sf);
        float a = kf * cosf(theta), b = kf * sinf(theta);
        float d = (float)(t - 16);
        float env = expf(-0.5f * d * d / (sf * sf));
        float v;
        switch (tbl) {
            case 0: v =  env * cosf(b * d); break;
            case 1: v =  env * sinf(b * d); break;
            case 2: v =  env * cosf(a * d); break;
            case 3: v =  env * sinf(a * d); break;
            default: v = -env * sinf(a * d); break;
        }
        P[tbl][t + 64] = (_Float16)v;
    }
    __syncthreads();
    unsigned* dst = tabs + (size_t)fo * 3200;
    for (int e = tid; e < 3200; e += 256) {
        int tbl  = e / 640;  int rem2 = e - tbl * 640;
        int copy = rem2 / 80; int idw = rem2 - copy * 80;
        int p0 = (idw >> 2) * 8 + copy + (idw & 3) * 2;   // = t0 + 64
        union { unsigned u; _Float16 h[2]; } p;
        p.h[0] = P[tbl][p0];
        p.h[1] = P[tbl][p0 + 1];
        dst[e] = p.u;
    }
}

// ---------------------------------------------------------------------------
// Fused kernel: S0 pool + MFMA separable Gabor conv + |.| + pool -> S1.
// 1536 blocks = (n:8)(tile:64)(fsplit:3), 512 threads, ~11 filters per block.
// LDS 47.3 KB -> 3 blocks/CU.  R12: float4-vectorized staging; cross-filter
// G-fragment prefetch (only remaining exposed global latency in the loop).
// ---------------------------------------------------------------------------
__launch_bounds__(512, 6)
__global__ void conv_kernel(const float* __restrict__ x,
                            const uint4* __restrict__ tabs,
                            float* __restrict__ s0out,
                            float* __restrict__ s1out) {
    __shared__ _Float16 gray[96 * GS];   // 19968 B
    __shared__ _Float16 Tre [64 * GS];   // 13312 B  (T^T: [col c][row m])
    __shared__ _Float16 Tim [64 * GS];   // 13312 B
    __shared__ float    s1st[11 * 16];   // 704 B, staged pooled outputs

    const int bx = blockIdx.x;
    const int n  = bx / 192;
    const int rem = bx - n * 192;
    const int t6 = rem / 3;
    const int fs = rem - t6 * 3;
    const int f0 = (fs * NFILT) / 3;          // 0, 10, 21
    const int f1 = ((fs + 1) * NFILT) / 3;    // 10, 21, 32
    const int ty = t6 >> 3, tx = t6 & 7;
    const int r0g = ty * 64 - 16;
    const int c0g = tx * 64 - 16;             // 16-aligned -> float4-aligned
    const int tid = threadIdx.x;

    // ---- stage gray = 3-channel mean (f16), float4 loads, group bounds ----
    // tasks: 96 rows x 24 col-groups of 4; cols 96..103 of GS never read.
    {
        const float* c0p = x + (size_t)n * 3 * IMG * IMG;
        const float* c1p = c0p + IMG * IMG;
        const float* c2p = c0p + 2 * IMG * IMG;
        for (int e = tid; e < 96 * 24; e += 512) {
            int hr = e / 24, g4 = e - hr * 24;
            int hc0 = g4 * 4;
            int gr = r0g + hr, gc0 = c0g + hc0;
            float4 v = make_float4(0.f, 0.f, 0.f, 0.f);
            if (hr < 95 && (unsigned)gr < IMG && (unsigned)gc0 < IMG) {
                size_t off = ((size_t)gr * IMG + gc0) >> 2;
                float4 a = ((const float4*)c0p)[off];
                float4 b = ((const float4*)c1p)[off];
                float4 c = ((const float4*)c2p)[off];
                v.x = (a.x + b.x + c.x) * (1.0f / 3.0f);
                v.y = (a.y + b.y + c.y) * (1.0f / 3.0f);
                v.z = (a.z + b.z + c.z) * (1.0f / 3.0f);
                v.w = (hc0 == 92) ? 0.0f : (a.w + b.w + c.w) * (1.0f / 3.0f);
            }
            uint2 w2;
            w2.x = pkrtz(v.x, v.y);
            w2.y = pkrtz(v.z, v.w);
            *(uint2*)(&gray[hr * GS + hc0]) = w2;
        }
    }
    __syncthreads();

    // ---- fused S0 (only fsplit 0): 16x16 avg-pool of gray interior ----
    if (fs == 0 && tid < 256) {
        int cell = tid >> 4, sub = tid & 15;
        int pr = cell >> 2, pc = cell & 3;
        const _Float16* row = &gray[(16 + pr * 16 + sub) * GS + 16 + pc * 16];
        float s = 0.0f;
        #pragma unroll
        for (int j = 0; j < 16; ++j) s += (float)row[j];
        s += __shfl_xor(s, 1);
        s += __shfl_xor(s, 2);
        s += __shfl_xor(s, 4);
        s += __shfl_xor(s, 8);
        if (sub == 0)
            s0out[(size_t)n * 1024 + (ty * 4 + pr) * 32 + (tx * 4 + pc)] = s * (1.0f / 256.0f);
    }

    const int lane = tid & 63;
    const int w    = tid >> 6;
    const int r4   = w & 3;                 // pass A N-tile / pass B M-tile
    const int half = w >> 2;                // splits mt (pass A) / nt (pass B)
    const int nn   = lane & 15;
    const int q8   = (lane >> 4) << 3;      // k-offset within K=32 fragment
    const int q4   = (lane >> 4) << 2;      // C/D row base within 16-tile
    const int cr   = r4 * 16 + nn;          // pass A: col c; pass B: row r
    const int u    = q8 - cr + 64;          // tap-phase for fragment tables
    const int b0   = r4 >> 1;               // first needed k-block (band skip)
    const int uoff = (u & 7) * 20 + (u >> 3);

    v8h GreA[2], GimA[2], GreB[2], GimB[2];   // rotating G prefetch sets

#define PREFG(SET, F)                                                         \
    {                                                                         \
        const uint4* fbg = tabs + (size_t)(F) * 800 + uoff;                   \
        _Pragma("unroll")                                                     \
        for (int j = 0; j < 2; ++j) {                                         \
            int idx = (b0 + j) * 4;                                           \
            Gre##SET[j] = ldfrag(fbg + idx);                                  \
            Gim##SET[j] = ldfrag(fbg + 160 + idx);                            \
        }                                                                     \
    }

#define STEP(CUR, NXT, F, DOPF)                                               \
    {                                                                         \
        if (DOPF) PREFG(NXT, (F) + 1);                                        \
        const uint4* fb = tabs + (size_t)(F) * 800 + uoff;                    \
        /* pass A: T = gray . G (A-operand from LDS, G resident) */           \
        _Pragma("unroll")                                                     \
        for (int mi = 0; mi < 3; ++mi) {                                      \
            int mt = half * 3 + mi;                                           \
            v4f aR = {0.f, 0.f, 0.f, 0.f}, aI = {0.f, 0.f, 0.f, 0.f};         \
            _Pragma("unroll")                                                 \
            for (int j = 0; j < 2; ++j) {                                     \
                v8h Ag = *(const v8h*)(&gray[(mt * 16 + nn) * GS + (b0 + j) * 32 + q8]); \
                aR = __builtin_amdgcn_mfma_f32_16x16x32_f16(Ag, Gre##CUR[j], aR, 0, 0, 0); \
                aI = __builtin_amdgcn_mfma_f32_16x16x32_f16(Ag, Gim##CUR[j], aI, 0, 0, 0); \
            }                                                                 \
            int mb = mt * 16 + q4;                                            \
            uint2 pr, pi;                                                     \
            pr.x = pkrtz(aR[0], aR[1]);  pr.y = pkrtz(aR[2], aR[3]);          \
            pi.x = pkrtz(aI[0], aI[1]);  pi.y = pkrtz(aI[2], aI[3]);          \
            *(uint2*)(&Tre[cr * GS + mb]) = pr;                               \
            *(uint2*)(&Tim[cr * GS + mb]) = pi;                               \
        }                                                                     \
        /* phase 2: F fragments (latency spans pass-A tail + barrier) */      \
        v8h Fre[2], Fim[2];                                                   \
        _Pragma("unroll")                                                     \
        for (int j = 0; j < 2; ++j) {                                         \
            int idx = (b0 + j) * 4;                                           \
            Fre[j] = ldfrag(fb + 320 + idx);                                  \
            Fim[j] = ldfrag(fb + 480 + idx);                                  \
        }                                                                     \
        __syncthreads();                                                      \
        v8h FiN[2];                                                           \
        FiN[0] = neg8h(Fim[0]);                                               \
        FiN[1] = neg8h(Fim[1]);                                               \
        /* pass B: Out = F . T */                                             \
        _Pragma("unroll")                                                     \
        for (int ni = 0; ni < 2; ++ni) {                                      \
            int nt = half * 2 + ni;                                           \
            v4f cR = {0.f, 0.f, 0.f, 0.f}, cI = {0.f, 0.f, 0.f, 0.f};         \
            _Pragma("unroll")                                                 \
            for (int j = 0; j < 2; ++j) {                                     \
                v8h tR = *(const v8h*)(&Tre[(nt * 16 + nn) * GS + (b0 + j) * 32 + q8]); \
                v8h tI = *(const v8h*)(&Tim[(nt * 16 + nn) * GS + (b0 + j) * 32 + q8]); \
                cR = __builtin_amdgcn_mfma_f32_16x16x32_f16(Fre[j], tR, cR, 0, 0, 0); \
                cR = __builtin_amdgcn_mfma_f32_16x16x32_f16(FiN[j], tI, cR, 0, 0, 0); \
                cI = __builtin_amdgcn_mfma_f32_16x16x32_f16(Fre[j], tI, cI, 0, 0, 0); \
                cI = __builtin_amdgcn_mfma_f32_16x16x32_f16(Fim[j], tR, cI, 0, 0, 0); \
            }                                                                 \
            float m = 0.0f;                                                   \
            _Pragma("unroll")                                                 \
            for (int r = 0; r < 4; ++r)                                       \
                m += fsqrt(fmaf(cR[r], cR[r], fmaf(cI[r], cI[r], 1e-8f)));    \
            m = dpp_add<0xB1>(m);   /* quad_perm xor1 */                      \
            m = dpp_add<0x4E>(m);   /* quad_perm xor2 */                      \
            m = dpp_add<0x141>(m);  /* row_half_mirror */                     \
            m = dpp_add<0x140>(m);  /* row_mirror */                          \
            m += __shfl_xor(m, 16);                                           \
            m += __shfl_xor(m, 32);                                           \
            if (lane == 0)                                                    \
                s1st[((F) - f0) * 16 + r4 * 4 + nt] = m;                      \
        }                                                                     \
        __syncthreads();                    /* T overwritten next filter */   \
    }

    PREFG(A, f0);
    int fo = f0;
    while (fo + 2 <= f1) {
        STEP(A, B, fo, true);
        STEP(B, A, fo + 1, (fo + 2 < f1));
        fo += 2;
    }
    if (fo < f1) STEP(A, B, fo, false);
#undef STEP
#undef PREFG

    // ---- epilogue: flush staged S1 (loop ended with a barrier) ----
    float* s1b = s1out + (size_t)n * NFILT * 32 * 32;
    const int nf = f1 - f0;
    for (int e = tid; e < nf * 16; e += 512) {
        int fi = e >> 4, cell = e & 15;
        int r4c = cell >> 2, ntc = cell & 3;
        s1b[((size_t)(f0 + fi) * 32 + (ty * 4 + r4c)) * 32 + (tx * 4 + ntc)] =
            s1st[e] * (1.0f / 256.0f);
    }
}

// ---------------------------------------------------------------------------
extern "C" void kernel_launch(void* const* d_in, const int* in_sizes, int n_in,
                              void* d_out, int out_size, void* d_ws, size_t ws_size,
                              hipStream_t stream) {
    const float* x = (const float*)d_in[0];
    float* out = (float*)d_out;
    unsigned* tabs = (unsigned*)d_ws;          // 102400 dwords = 400 KB scratch

    hipLaunchKernelGGL(make_tables, dim3(32), dim3(256), 0, stream, tabs);
    hipLaunchKernelGGL(conv_kernel, dim3(1536), dim3(512), 0, stream,
                       x, (const uint4*)tabs, out, out + 8192);
}

// Round 13
// 173.735 us; speedup vs baseline: 1.3622x; 1.3622x over previous
//
#include <hip/hip_runtime.h>
#include <math.h>

#define IMG   512
#define NFILT 32
#define PI_F  3.14159265358979323846f
#define GS    104      // LDS row stride in halves (208 B): b128 across lanes = 2-way banks (free)

typedef _Float16 v8h __attribute__((ext_vector_type(8)));
typedef float    v4f __attribute__((ext_vector_type(4)));

__device__ __forceinline__ unsigned pkrtz(float a, float b) {
    typedef __fp16 f16x2 __attribute__((ext_vector_type(2)));
    union { f16x2 h; unsigned u; } x;
    x.h = __builtin_amdgcn_cvt_pkrtz(a, b);
    return x.u;
}

template <int CTRL>
__device__ __forceinline__ float dpp_add(float v) {
    int t = __builtin_amdgcn_update_dpp(0, __float_as_int(v), CTRL, 0xf, 0xf, true);
    return v + __int_as_float(t);
}

#if __has_builtin(__builtin_amdgcn_sqrtf)
__device__ __forceinline__ float fsqrt(float x) { return __builtin_amdgcn_sqrtf(x); }
#else
__device__ __forceinline__ float fsqrt(float x) { return sqrtf(x); }
#endif

__device__ __forceinline__ v8h ldfrag(const uint4* p) {
    union { uint4 u; v8h h; } x; x.u = *p; return x.h;
}

__device__ __forceinline__ v8h neg8h(v8h a) {           // flip f16 sign bits
    union { v8h h; uint4 u; } x; x.h = a;
    x.u.x ^= 0x80008000u; x.u.y ^= 0x80008000u;
    x.u.z ^= 0x80008000u; x.u.w ^= 0x80008000u;
    return x.h;
}

// ---------------------------------------------------------------------------
// tabs layout (dwords): [filter:32][table:5][copy:8][block:20][dw:4]
//   tables: 0 g_re, 1 g_im, 2 f_re, 3 f_im, 4 -f_im (tbl4 kept for layout)
//   copy c, block i holds halves tap(8*i-64+c .. +7); tap(t)=0 unless 0<=t<32.
// One block per filter: compute 160 base taps into LDS once, expand by gather.
// ---------------------------------------------------------------------------
__global__ void make_tables(unsigned* __restrict__ tabs) {
    __shared__ _Float16 P[5][168];      // P[tbl][p] = tap(p-64), zero-padded
    const int fo = blockIdx.x;
    const int tid = threadIdx.x;
    for (int e = tid; e < 5 * 168; e += 256) ((_Float16*)P)[e] = (_Float16)0.0f;
    __syncthreads();
    if (tid < 160) {
        int tbl = tid >> 5, t = tid & 31;
        int s = (fo >> 3) + 1, o = fo & 7;
        float theta = (float)o * (PI_F / 7.0f);      // linspace(0, pi, 8)
        float sf = (float)s * 2.0f;                  // scale * SIGMA
        float kf = 2.0f * PI_F / ((float)s * sf);
        float a = kf * cosf(theta), b = kf * sinf(theta);
        float d = (float)(t - 16);
        float env = expf(-0.5f * d * d / (sf * sf));
        float v;
        switch (tbl) {
            case 0: v =  env * cosf(b * d); break;
            case 1: v =  env * sinf(b * d); break;
            case 2: v =  env * cosf(a * d); break;
            case 3: v =  env * sinf(a * d); break;
            default: v = -env * sinf(a * d); break;
        }
        P[tbl][t + 64] = (_Float16)v;
    }
    __syncthreads();
    unsigned* dst = tabs + (size_t)fo * 3200;
    for (int e = tid; e < 3200; e += 256) {
        int tbl  = e / 640;  int rem2 = e - tbl * 640;
        int copy = rem2 / 80; int idw = rem2 - copy * 80;
        int p0 = (idw >> 2) * 8 + copy + (idw & 3) * 2;   // = t0 + 64
        union { unsigned u; _Float16 h[2]; } p;
        p.h[0] = P[tbl][p0];
        p.h[1] = P[tbl][p0 + 1];
        dst[e] = p.u;
    }
}

// ---------------------------------------------------------------------------
// Fused kernel: S0 pool + MFMA separable Gabor conv + |.| + pool -> S1.
// 1536 blocks = (n:8)(tile:64)(fsplit:3), 512 threads, ~11 filters per block.
// LDS 47.3 KB -> 3 blocks/CU.  R13 = R11 loop (no cross-filter register
// prefetch -- spills at the 84-VGPR cap) + float4-vectorized gray staging.
// ---------------------------------------------------------------------------
__launch_bounds__(512, 6)
__global__ void conv_kernel(const float* __restrict__ x,
                            const uint4* __restrict__ tabs,
                            float* __restrict__ s0out,
                            float* __restrict__ s1out) {
    __shared__ _Float16 gray[96 * GS];   // 19968 B
    __shared__ _Float16 Tre [64 * GS];   // 13312 B  (T^T: [col c][row m])
    __shared__ _Float16 Tim [64 * GS];   // 13312 B
    __shared__ float    s1st[11 * 16];   // 704 B, staged pooled outputs

    const int bx = blockIdx.x;
    const int n  = bx / 192;
    const int rem = bx - n * 192;
    const int t6 = rem / 3;
    const int fs = rem - t6 * 3;
    const int f0 = (fs * NFILT) / 3;          // 0, 10, 21
    const int f1 = ((fs + 1) * NFILT) / 3;    // 10, 21, 32
    const int ty = t6 >> 3, tx = t6 & 7;
    const int r0g = ty * 64 - 16;
    const int c0g = tx * 64 - 16;             // 16-aligned -> float4-aligned
    const int tid = threadIdx.x;

    // ---- stage gray = 3-channel mean (f16), float4 loads, group bounds ----
    // tasks: 96 rows x 24 col-groups of 4; cols 96..103 of GS never read.
    {
        const float* c0p = x + (size_t)n * 3 * IMG * IMG;
        const float* c1p = c0p + IMG * IMG;
        const float* c2p = c0p + 2 * IMG * IMG;
        for (int e = tid; e < 96 * 24; e += 512) {
            int hr = e / 24, g4 = e - hr * 24;
            int hc0 = g4 * 4;
            int gr = r0g + hr, gc0 = c0g + hc0;
            float4 v = make_float4(0.f, 0.f, 0.f, 0.f);
            if (hr < 95 && (unsigned)gr < IMG && (unsigned)gc0 < IMG) {
                size_t off = ((size_t)gr * IMG + gc0) >> 2;
                float4 a = ((const float4*)c0p)[off];
                float4 b = ((const float4*)c1p)[off];
                float4 c = ((const float4*)c2p)[off];
                v.x = (a.x + b.x + c.x) * (1.0f / 3.0f);
                v.y = (a.y + b.y + c.y) * (1.0f / 3.0f);
                v.z = (a.z + b.z + c.z) * (1.0f / 3.0f);
                v.w = (hc0 == 92) ? 0.0f : (a.w + b.w + c.w) * (1.0f / 3.0f);
            }
            uint2 w2;
            w2.x = pkrtz(v.x, v.y);
            w2.y = pkrtz(v.z, v.w);
            *(uint2*)(&gray[hr * GS + hc0]) = w2;
        }
    }
    __syncthreads();

    // ---- fused S0 (only fsplit 0): 16x16 avg-pool of gray interior ----
    if (fs == 0 && tid < 256) {
        int cell = tid >> 4, sub = tid & 15;
        int pr = cell >> 2, pc = cell & 3;
        const _Float16* row = &gray[(16 + pr * 16 + sub) * GS + 16 + pc * 16];
        float s = 0.0f;
        #pragma unroll
        for (int j = 0; j < 16; ++j) s += (float)row[j];
        s += __shfl_xor(s, 1);
        s += __shfl_xor(s, 2);
        s += __shfl_xor(s, 4);
        s += __shfl_xor(s, 8);
        if (sub == 0)
            s0out[(size_t)n * 1024 + (ty * 4 + pr) * 32 + (tx * 4 + pc)] = s * (1.0f / 256.0f);
    }

    const int lane = tid & 63;
    const int w    = tid >> 6;
    const int r4   = w & 3;                 // pass A N-tile / pass B M-tile
    const int half = w >> 2;                // splits mt (pass A) / nt (pass B)
    const int nn   = lane & 15;
    const int q8   = (lane >> 4) << 3;      // k-offset within K=32 fragment
    const int q4   = (lane >> 4) << 2;      // C/D row base within 16-tile
    const int cr   = r4 * 16 + nn;          // pass A: col c; pass B: row r
    const int u    = q8 - cr + 64;          // tap-phase for fragment tables
    const int b0   = r4 >> 1;               // first needed k-block (band skip)
    const int uoff = (u & 7) * 20 + (u >> 3);

    // ---- hoist filter-invariant gray A-fragments into registers ----
    v8h Agray[3][2];
    #pragma unroll
    for (int mi = 0; mi < 3; ++mi)
        #pragma unroll
        for (int j = 0; j < 2; ++j)
            Agray[mi][j] = *(const v8h*)(&gray[((half * 3 + mi) * 16 + nn) * GS + (b0 + j) * 32 + q8]);

    for (int fo = f0; fo < f1; ++fo) {
        const uint4* fb = tabs + (size_t)fo * 800 + uoff;

        // ---- phase 1: G fragments ----
        v8h Gre[2], Gim[2];
        #pragma unroll
        for (int j = 0; j < 2; ++j) {
            int idx = (b0 + j) * 4;
            Gre[j] = ldfrag(fb + idx);
            Gim[j] = ldfrag(fb + 160 + idx);
        }

        // ---- pass A: T = gray . G  (A-operand from registers) ----
        #pragma unroll
        for (int mi = 0; mi < 3; ++mi) {
            int mt = half * 3 + mi;
            v4f aR = {0.f, 0.f, 0.f, 0.f}, aI = {0.f, 0.f, 0.f, 0.f};
            #pragma unroll
            for (int j = 0; j < 2; ++j) {
                aR = __builtin_amdgcn_mfma_f32_16x16x32_f16(Agray[mi][j], Gre[j], aR, 0, 0, 0);
                aI = __builtin_amdgcn_mfma_f32_16x16x32_f16(Agray[mi][j], Gim[j], aI, 0, 0, 0);
            }
            // C/D: col=lane&15 -> c=cr, row=q4+reg -> m; write T^T[c][m] 4 halves
            int mb = mt * 16 + q4;
            uint2 pr, pi;
            pr.x = pkrtz(aR[0], aR[1]);  pr.y = pkrtz(aR[2], aR[3]);
            pi.x = pkrtz(aI[0], aI[1]);  pi.y = pkrtz(aI[2], aI[3]);
            *(uint2*)(&Tre[cr * GS + mb]) = pr;
            *(uint2*)(&Tim[cr * GS + mb]) = pi;
        }

        // ---- phase 2: F fragments (latency spans pass-A tail + barrier) ----
        v8h Fre[2], Fim[2];
        #pragma unroll
        for (int j = 0; j < 2; ++j) {
            int idx = (b0 + j) * 4;
            Fre[j] = ldfrag(fb + 320 + idx);
            Fim[j] = ldfrag(fb + 480 + idx);
        }
        __syncthreads();
        v8h FiN[2];
        FiN[0] = neg8h(Fim[0]);
        FiN[1] = neg8h(Fim[1]);

        // ---- pass B: Out = F . T  (wave: M-tile r4, nt in half's range) ----
        #pragma unroll
        for (int ni = 0; ni < 2; ++ni) {
            int nt = half * 2 + ni;
            v4f cR = {0.f, 0.f, 0.f, 0.f}, cI = {0.f, 0.f, 0.f, 0.f};
            #pragma unroll
            for (int j = 0; j < 2; ++j) {
                v8h tR = *(const v8h*)(&Tre[(nt * 16 + nn) * GS + (b0 + j) * 32 + q8]);
                v8h tI = *(const v8h*)(&Tim[(nt * 16 + nn) * GS + (b0 + j) * 32 + q8]);
                cR = __builtin_amdgcn_mfma_f32_16x16x32_f16(Fre[j], tR, cR, 0, 0, 0);
                cR = __builtin_amdgcn_mfma_f32_16x16x32_f16(FiN[j], tI, cR, 0, 0, 0);
                cI = __builtin_amdgcn_mfma_f32_16x16x32_f16(Fre[j], tI, cI, 0, 0, 0);
                cI = __builtin_amdgcn_mfma_f32_16x16x32_f16(Fim[j], tR, cI, 0, 0, 0);
            }
            // magnitude + full 16x16-cell pool (cell = (r4, nt)); stage in LDS
            float m = 0.0f;
            #pragma unroll
            for (int r = 0; r < 4; ++r)
                m += fsqrt(fmaf(cR[r], cR[r], fmaf(cI[r], cI[r], 1e-8f)));
            m = dpp_add<0xB1>(m);   // quad_perm xor1
            m = dpp_add<0x4E>(m);   // quad_perm xor2
            m = dpp_add<0x141>(m);  // row_half_mirror
            m = dpp_add<0x140>(m);  // row_mirror
            m += __shfl_xor(m, 16);
            m += __shfl_xor(m, 32);
            if (lane == 0)
                s1st[(fo - f0) * 16 + r4 * 4 + nt] = m;
        }
        __syncthreads();                    // T overwritten next filter
    }

    // ---- epilogue: flush staged S1 (loop ended with a barrier) ----
    float* s1b = s1out + (size_t)n * NFILT * 32 * 32;
    const int nf = f1 - f0;
    for (int e = tid; e < nf * 16; e += 512) {
        int fi = e >> 4, cell = e & 15;
        int r4c = cell >> 2, ntc = cell & 3;
        s1b[((size_t)(f0 + fi) * 32 + (ty * 4 + r4c)) * 32 + (tx * 4 + ntc)] =
            s1st[e] * (1.0f / 256.0f);
    }
}

// ---------------------------------------------------------------------------
extern "C" void kernel_launch(void* const* d_in, const int* in_sizes, int n_in,
                              void* d_out, int out_size, void* d_ws, size_t ws_size,
                              hipStream_t stream) {
    const float* x = (const float*)d_in[0];
    float* out = (float*)d_out;
    unsigned* tabs = (unsigned*)d_ws;          // 102400 dwords = 400 KB scratch

    hipLaunchKernelGGL(make_tables, dim3(32), dim3(256), 0, stream, tabs);
    hipLaunchKernelGGL(conv_kernel, dim3(1536), dim3(512), 0, stream,
                       x, (const uint4*)tabs, out, out + 8192);
}